// Round 7
// 2112.479 us; speedup vs baseline: 1.2536x; 1.2536x over previous
//
#include <hip/hip_runtime.h>

typedef __attribute__((ext_vector_type(8))) _Float16 half8;
typedef __attribute__((ext_vector_type(2))) __fp16 fp16x2;   // cvt_pkrtz return type
typedef __attribute__((ext_vector_type(4))) float floatx4;
typedef __attribute__((ext_vector_type(4))) unsigned int uintx4;

constexpr int Mdim = 8192;    // B*S
constexpr int Kdim = 4096;    // IN
constexpr int Ndim = 11008;   // OUT
constexpr int BM = 128, BN = 128, BK = 64;
constexpr int NGRP = 32;      // IN/GROUP
constexpr int NBX = Ndim / BN;   // 86
constexpr int NBY = Mdim / BM;   // 64
constexpr int GN  = 8;           // N-blocks per supergroup (M-fastest inside)

__device__ __forceinline__ unsigned pk2(float a, float b) {
    // v_cvt_pkrtz_f16_f32: 2 f32 -> packed 2x f16 in ONE VALU op.
    // A values originated as fp16 -> conversion is exact. W*s: 10-bit mantissa
    // RTZ, better than the previous bf16 RNE (8-bit).
    fp16x2 h = __builtin_amdgcn_cvt_pkrtz(a, b);
    return __builtin_bit_cast(unsigned, h);
}

// Fused dequant + f16 MFMA GEMM. Zero workspace.
// C[M][N] = A[M][K] * (W[N][K] * scale[N][K/128])^T + bias
__global__ __launch_bounds__(256) void wq8_gemm_kernel(
        const float* __restrict__ A,      // [M][K] fp32 (fp16 widened)
        const int* __restrict__ W,        // [N][K] int32 (int8 widened)
        const float* __restrict__ scale,  // [N][NGRP] fp32
        const float* __restrict__ bias,   // [N] fp32
        float* __restrict__ C) {          // [M][N] fp32
    __shared__ unsigned short sA[BM * BK];
    __shared__ unsigned short sB[BN * BK];

    // ---- grid swizzle: supergroups of GN x-blocks, M(y)-fastest inside ----
    // Working set per group: W chunk = GN*2 MiB (hot), A = 128 MiB (L3-resident
    // across groups). C stores are nontemporal so they don't evict W/A from L3.
    const int bid   = blockIdx.x;
    const int gsz   = GN * NBY;
    const int grpid = bid / gsz;
    const int rem   = bid - grpid * gsz;
    const int bx    = grpid * GN + rem / NBY;   // last group is narrower (86%8=6) — mapping stays bijective
    const int by    = rem % NBY;
    const int m0 = by * BM;
    const int n0 = bx * BN;

    const int tid  = threadIdx.x;
    const int lane = tid & 63;
    const int wave = tid >> 6;

    // staging map: thread covers row = (tid>>3) + 32*it, elem cols (tid&7)*8 .. +7
    const int srow = tid >> 3;          // 0..31
    const int scol = (tid & 7) * 8;     // element offset in K
    // T2 XOR swizzle (elem units; 8-elem = 16B chunks, bits 3..5):
    // row&7 is srow&7 for all 4 'it' slices (it*32 keeps low 3 row bits).
    const int sOff = scol ^ ((srow & 7) << 3);

    const int wm = (wave >> 1) * 64;    // 2x2 waves over 128x128
    const int wn = (wave & 1) * 64;
    const int fr = lane & 15;           // frag row (m for A, n for B), and C col
    const int fkb = (lane >> 4) * 8;    // frag k elem offset
    // read-side swizzle: all rows read are wm/wn + i*16 + fr (multiples of 8 + fr)
    const int swz_r = (fr & 7) << 3;

    floatx4 acc[4][4] = {};

    const float* ga0 = A + (long)(m0 + srow) * Kdim + scol;
    const int*   gw0 = W + (long)(n0 + srow) * Kdim + scol;

    for (int k0 = 0; k0 < Kdim; k0 += BK) {
        const int grp = k0 >> 7;        // BK=64 <= GROUP=128: one scale per tile

        // ---- load A tile (fp32) and W tile (int32) ----
        float4 rax[4][2];
        int4   rw[4][2];
        float  sc[4];
        #pragma unroll
        for (int it = 0; it < 4; ++it) {
            const float* ap = ga0 + (long)it * 32 * Kdim + k0;
            rax[it][0] = *(const float4*)(ap);
            rax[it][1] = *(const float4*)(ap + 4);
            const int* wp = gw0 + (long)it * 32 * Kdim + k0;
            rw[it][0] = *(const int4*)(wp);
            rw[it][1] = *(const int4*)(wp + 4);
            sc[it] = scale[(long)(n0 + srow + it * 32) * NGRP + grp];
        }

        // ---- stage: A fp32->f16 (pkrtz, exact), W dequant->f16 ----
        #pragma unroll
        for (int it = 0; it < 4; ++it) {
            uintx4 av;
            av.x = pk2(rax[it][0].x, rax[it][0].y);
            av.y = pk2(rax[it][0].z, rax[it][0].w);
            av.z = pk2(rax[it][1].x, rax[it][1].y);
            av.w = pk2(rax[it][1].z, rax[it][1].w);
            *(uintx4*)(sA + (srow + it * 32) * BK + sOff) = av;

            const float s = sc[it];
            uintx4 wv;
            wv.x = pk2((float)rw[it][0].x * s, (float)rw[it][0].y * s);
            wv.y = pk2((float)rw[it][0].z * s, (float)rw[it][0].w * s);
            wv.z = pk2((float)rw[it][1].x * s, (float)rw[it][1].y * s);
            wv.w = pk2((float)rw[it][1].z * s, (float)rw[it][1].w * s);
            *(uintx4*)(sB + (srow + it * 32) * BK + sOff) = wv;
        }
        __syncthreads();

        #pragma unroll
        for (int kk = 0; kk < BK; kk += 32) {
            half8 af[4], bfr[4];
            #pragma unroll
            for (int i = 0; i < 4; ++i)
                af[i] = *(const half8*)(sA + (wm + i * 16 + fr) * BK + ((kk + fkb) ^ swz_r));
            #pragma unroll
            for (int j = 0; j < 4; ++j)
                bfr[j] = *(const half8*)(sB + (wn + j * 16 + fr) * BK + ((kk + fkb) ^ swz_r));
            #pragma unroll
            for (int i = 0; i < 4; ++i)
                #pragma unroll
                for (int j = 0; j < 4; ++j)
                    acc[i][j] = __builtin_amdgcn_mfma_f32_16x16x32_f16(
                        af[i], bfr[j], acc[i][j], 0, 0, 0);
        }
        __syncthreads();
    }

    // epilogue: C/D layout col=lane&15, row=(lane>>4)*4+reg  [m89/m91]
    float bv[4];
    #pragma unroll
    for (int j = 0; j < 4; ++j)
        bv[j] = bias[n0 + wn + j * 16 + fr];

    const int r0 = (lane >> 4) * 4;
    #pragma unroll
    for (int i = 0; i < 4; ++i) {
        #pragma unroll
        for (int r = 0; r < 4; ++r) {
            long row = m0 + wm + i * 16 + r0 + r;
            float* cp = C + row * Ndim + n0 + wn + fr;
            #pragma unroll
            for (int j = 0; j < 4; ++j)
                __builtin_nontemporal_store(acc[i][j][r] + bv[j], cp + j * 16);
        }
    }
}

extern "C" void kernel_launch(void* const* d_in, const int* in_sizes, int n_in,
                              void* d_out, int out_size, void* d_ws, size_t ws_size,
                              hipStream_t stream) {
    const float* x     = (const float*)d_in[0];  // fp32 [B,S,IN]
    const int*   w     = (const int*)d_in[1];    // int32 [OUT,IN]
    const float* scale = (const float*)d_in[2];  // fp32 [OUT,IN/128]
    const float* bias  = (const float*)d_in[3];  // fp32 [OUT]
    float* out = (float*)d_out;                  // fp32 [B,S,OUT]

    wq8_gemm_kernel<<<dim3(NBX * NBY), 256, 0, stream>>>(x, w, scale, bias, out);
}

// Round 8
// 1689.072 us; speedup vs baseline: 1.5678x; 1.2507x over previous
//
#include <hip/hip_runtime.h>

typedef __attribute__((ext_vector_type(8))) _Float16 half8;
typedef __attribute__((ext_vector_type(2))) __fp16 fp16x2;   // cvt_pkrtz return type
typedef __attribute__((ext_vector_type(4))) float floatx4;
typedef __attribute__((ext_vector_type(4))) unsigned int uintx4;

constexpr int Mdim = 8192;    // B*S
constexpr int Kdim = 4096;    // IN
constexpr int Ndim = 11008;   // OUT
constexpr int BM = 256, BN = 256, BK = 64;
constexpr int NGRP = 32;      // IN/GROUP
constexpr int NBX = Ndim / BN;   // 43
constexpr int NBY = Mdim / BM;   // 32
constexpr int GN  = 8;           // N-blocks per supergroup (M-fastest inside)
constexpr int NT  = Kdim / BK;   // 64 K-tiles

__device__ __forceinline__ unsigned pk2(float a, float b) {
    // v_cvt_pkrtz_f16_f32: 2 f32 -> packed 2x f16 in ONE VALU op.
    fp16x2 h = __builtin_amdgcn_cvt_pkrtz(a, b);
    return __builtin_bit_cast(unsigned, h);
}

// Fused dequant + f16 MFMA GEMM, 256x256 tile, 8 waves, double-buffered LDS,
// ONE barrier per K-tile, global loads for t+1 issued before MFMA phase of t
// (T14 issue-early: HBM latency hides under 64 MFMAs/wave).
// C[M][N] = A[M][K] * (W[N][K] * scale[N][K/128])^T + bias
__global__ __launch_bounds__(512) void wq8_gemm_kernel(
        const float* __restrict__ A,      // [M][K] fp32 (fp16 widened)
        const int* __restrict__ W,        // [N][K] int32 (int8 widened)
        const float* __restrict__ scale,  // [N][NGRP] fp32
        const float* __restrict__ bias,   // [N] fp32
        float* __restrict__ C) {          // [M][N] fp32
    __shared__ unsigned short sA[2][BM * BK];   // 2 x 32 KiB
    __shared__ unsigned short sB[2][BN * BK];   // 2 x 32 KiB  (128 KiB total)

    // ---- grid swizzle: supergroups of GN x-blocks, M(y)-fastest inside ----
    // 1 block/CU -> concurrent window (256 blocks) == one full supergroup:
    // A (134 MiB) stays L3-resident across supergroups; W chunk 8 MiB hot.
    const int bid   = blockIdx.x;
    const int gsz   = GN * NBY;          // 256
    const int grpid = bid / gsz;
    const int rem   = bid - grpid * gsz;
    const int bx    = grpid * GN + rem / NBY;   // bijective incl. 43%8 tail
    const int by    = rem % NBY;
    const int m0 = by * BM;
    const int n0 = bx * BN;

    const int tid  = threadIdx.x;
    const int lane = tid & 63;
    const int wave = tid >> 6;          // 0..7

    // staging map: thread covers row = (tid>>3) + 64*it, elem cols (tid&7)*8 .. +7
    const int srow = tid >> 3;          // 0..63
    const int scol = (tid & 7) * 8;
    // T2 XOR swizzle (verified conflict-free in r7): row&7 == srow&7 for all it
    const int sOff = scol ^ ((srow & 7) << 3);

    const int wm = (wave >> 2) * 128;   // 2 wave-rows  (per-wave 128x64 output)
    const int wn = (wave & 3) * 64;     // 4 wave-cols
    const int fr = lane & 15;           // frag row (m for A, n for B), and C col
    const int fkb = (lane >> 4) * 8;    // frag k elem offset
    const int swz_r = (fr & 7) << 3;    // read-side swizzle: row&7 == fr&7

    floatx4 acc[8][4] = {};

    const float* ga0 = A + (long)(m0 + srow) * Kdim + scol;
    const int*   gw0 = W + (long)(n0 + srow) * Kdim + scol;

    // raw prefetch registers (live across the MFMA phase)
    float4 rax[4][2];
    int4   rw[4][2];
    float  sc[4];

    auto load_tile = [&](int k0) {
        const int grp = k0 >> 7;        // BK=64 <= GROUP=128
        #pragma unroll
        for (int it = 0; it < 4; ++it) {
            const float* ap = ga0 + (long)it * 64 * Kdim + k0;
            rax[it][0] = *(const float4*)(ap);
            rax[it][1] = *(const float4*)(ap + 4);
            const int* wp = gw0 + (long)it * 64 * Kdim + k0;
            rw[it][0] = *(const int4*)(wp);
            rw[it][1] = *(const int4*)(wp + 4);
            sc[it] = scale[(long)(n0 + srow + it * 64) * NGRP + grp];
        }
    };

    load_tile(0);

    for (int t = 0; t < NT; ++t) {
        unsigned short* bufA = sA[t & 1];
        unsigned short* bufB = sB[t & 1];

        // ---- convert + stage tile t (A fp32->f16 exact; W dequant->f16) ----
        #pragma unroll
        for (int it = 0; it < 4; ++it) {
            uintx4 av;
            av.x = pk2(rax[it][0].x, rax[it][0].y);
            av.y = pk2(rax[it][0].z, rax[it][0].w);
            av.z = pk2(rax[it][1].x, rax[it][1].y);
            av.w = pk2(rax[it][1].z, rax[it][1].w);
            *(uintx4*)(bufA + (srow + it * 64) * BK + sOff) = av;

            const float s = sc[it];
            uintx4 wv;
            wv.x = pk2((float)rw[it][0].x * s, (float)rw[it][0].y * s);
            wv.y = pk2((float)rw[it][0].z * s, (float)rw[it][0].w * s);
            wv.z = pk2((float)rw[it][1].x * s, (float)rw[it][1].y * s);
            wv.w = pk2((float)rw[it][1].z * s, (float)rw[it][1].w * s);
            *(uintx4*)(bufB + (srow + it * 64) * BK + sOff) = wv;
        }
        __syncthreads();   // single barrier/K-tile: next write targets the
                           // OTHER buffer, whose readers all passed this barrier

        // issue next tile's global loads; consumed next iteration (after 64
        // MFMAs) -> latency hidden, compiler places the vmcnt wait there
        if (t + 1 < NT) load_tile((t + 1) * BK);

        // ---- MFMA phase: 64 x mfma_16x16x32_f16 per wave ----
        #pragma unroll
        for (int kk = 0; kk < BK; kk += 32) {
            half8 af[8];
            #pragma unroll
            for (int i = 0; i < 8; ++i)
                af[i] = *(const half8*)(bufA + (wm + i * 16 + fr) * BK + ((kk + fkb) ^ swz_r));
            #pragma unroll
            for (int j = 0; j < 4; ++j) {
                half8 bf = *(const half8*)(bufB + (wn + j * 16 + fr) * BK + ((kk + fkb) ^ swz_r));
                #pragma unroll
                for (int i = 0; i < 8; ++i)
                    acc[i][j] = __builtin_amdgcn_mfma_f32_16x16x32_f16(
                        af[i], bf, acc[i][j], 0, 0, 0);
            }
        }
    }

    // epilogue: C/D layout col=lane&15, row=(lane>>4)*4+reg  [m89/m91]
    float bv[4];
    #pragma unroll
    for (int j = 0; j < 4; ++j)
        bv[j] = bias[n0 + wn + j * 16 + fr];

    const int r0 = (lane >> 4) * 4;
    #pragma unroll
    for (int i = 0; i < 8; ++i) {
        #pragma unroll
        for (int r = 0; r < 4; ++r) {
            long row = m0 + wm + i * 16 + r0 + r;
            float* cp = C + row * Ndim + n0 + wn + fr;
            #pragma unroll
            for (int j = 0; j < 4; ++j)
                __builtin_nontemporal_store(acc[i][j][r] + bv[j], cp + j * 16);
        }
    }
}

extern "C" void kernel_launch(void* const* d_in, const int* in_sizes, int n_in,
                              void* d_out, int out_size, void* d_ws, size_t ws_size,
                              hipStream_t stream) {
    const float* x     = (const float*)d_in[0];  // fp32 [B,S,IN]
    const int*   w     = (const int*)d_in[1];    // int32 [OUT,IN]
    const float* scale = (const float*)d_in[2];  // fp32 [OUT,IN/128]
    const float* bias  = (const float*)d_in[3];  // fp32 [OUT]
    float* out = (float*)d_out;                  // fp32 [B,S,OUT]

    wq8_gemm_kernel<<<dim3(NBX * NBY), 512, 0, stream>>>(x, w, scale, bias, out);
}

// Round 10
// 1645.216 us; speedup vs baseline: 1.6096x; 1.0267x over previous
//
#include <hip/hip_runtime.h>

typedef __attribute__((ext_vector_type(8))) _Float16 half8;
typedef __attribute__((ext_vector_type(2))) __fp16 fp16x2;   // cvt_pkrtz return type
typedef __attribute__((ext_vector_type(4))) float floatx4;
typedef __attribute__((ext_vector_type(4))) unsigned int uintx4;

constexpr int Mdim = 8192;    // B*S
constexpr int Kdim = 4096;    // IN
constexpr int Ndim = 11008;   // OUT
constexpr int BM = 256, BN = 256, BK = 64;
constexpr int NGRP = 32;      // IN/GROUP
constexpr int NBX = Ndim / BN;   // 43
constexpr int NBY = Mdim / BM;   // 32
constexpr int GN  = 8;           // N-blocks per supergroup (M-fastest inside)
constexpr int NT  = Kdim / BK;   // 64 K-tiles

__device__ __forceinline__ unsigned pk2(float a, float b) {
    fp16x2 h = __builtin_amdgcn_cvt_pkrtz(a, b);
    return __builtin_bit_cast(unsigned, h);
}

// Fused dequant + f16 MFMA GEMM, 256x256 tile, 8 waves, double-buffered LDS.
// In-tile software pipeline: MFMA(kk=0) | stage(t+1)+load(t+2) | MFMA(kk=32) |
// barrier.  Staging VALU overlaps the other wave's MFMA cluster (T5 setprio
// arbitrates).  One barrier per K-tile.
// C[M][N] = A[M][K] * (W[N][K] * scale[N][K/128])^T + bias
__global__ __launch_bounds__(512) void wq8_gemm_kernel(
        const float* __restrict__ A,      // [M][K] fp32 (fp16 widened)
        const int* __restrict__ W,        // [N][K] int32 (int8 widened)
        const float* __restrict__ scale,  // [N][NGRP] fp32
        const float* __restrict__ bias,   // [N] fp32
        float* __restrict__ C) {          // [M][N] fp32
    __shared__ unsigned short sA[2][BM * BK];   // 2 x 32 KiB
    __shared__ unsigned short sB[2][BN * BK];   // 2 x 32 KiB  (128 KiB total)

    // ---- grid swizzle: supergroups of GN x-blocks, M(y)-fastest inside ----
    const int bid   = blockIdx.x;
    const int gsz   = GN * NBY;          // 256
    const int grpid = bid / gsz;
    const int rem   = bid - grpid * gsz;
    const int bx    = grpid * GN + rem / NBY;   // bijective incl. 43%8 tail
    const int by    = rem % NBY;
    const int m0 = by * BM;
    const int n0 = bx * BN;

    const int tid  = threadIdx.x;
    const int lane = tid & 63;
    const int wave = tid >> 6;          // 0..7

    // staging map: thread covers row = (tid>>3) + 64*it, elem cols (tid&7)*8 .. +7
    const int srow = tid >> 3;          // 0..63
    const int scol = (tid & 7) * 8;
    // T2 XOR swizzle (conflicts measured 0 in r7/r8)
    const int sOff = scol ^ ((srow & 7) << 3);

    const int wm = (wave >> 2) * 128;   // per-wave 128x64 output
    const int wn = (wave & 3) * 64;
    const int fr = lane & 15;
    const int fkb = (lane >> 4) * 8;
    const int swz_r = (fr & 7) << 3;

    floatx4 acc[8][4] = {};

    const float* ga0 = A + (long)(m0 + srow) * Kdim + scol;
    const int*   gw0 = W + (long)(n0 + srow) * Kdim + scol;

    // raw prefetch registers (2 tiles ahead of consumption)
    float4 rax[4][2];
    int4   rw[4][2];
    float  sc[4];

    auto load_tile = [&](int k0) {
        const int grp = k0 >> 7;        // BK=64 <= GROUP=128
        #pragma unroll
        for (int it = 0; it < 4; ++it) {
            const float* ap = ga0 + (long)it * 64 * Kdim + k0;
            rax[it][0] = *(const float4*)(ap);
            rax[it][1] = *(const float4*)(ap + 4);
            const int* wp = gw0 + (long)it * 64 * Kdim + k0;
            rw[it][0] = *(const int4*)(wp);
            rw[it][1] = *(const int4*)(wp + 4);
            sc[it] = scale[(long)(n0 + srow + it * 64) * NGRP + grp];
        }
    };

    auto stage_tile = [&](unsigned short* bufA, unsigned short* bufB) {
        #pragma unroll
        for (int it = 0; it < 4; ++it) {
            uintx4 av;
            av.x = pk2(rax[it][0].x, rax[it][0].y);
            av.y = pk2(rax[it][0].z, rax[it][0].w);
            av.z = pk2(rax[it][1].x, rax[it][1].y);
            av.w = pk2(rax[it][1].z, rax[it][1].w);
            *(uintx4*)(bufA + (srow + it * 64) * BK + sOff) = av;

            const float s = sc[it];
            uintx4 wv;
            wv.x = pk2((float)rw[it][0].x * s, (float)rw[it][0].y * s);
            wv.y = pk2((float)rw[it][0].z * s, (float)rw[it][0].w * s);
            wv.z = pk2((float)rw[it][1].x * s, (float)rw[it][1].y * s);
            wv.w = pk2((float)rw[it][1].z * s, (float)rw[it][1].w * s);
            *(uintx4*)(bufB + (srow + it * 64) * BK + sOff) = wv;
        }
    };

    // half-tile MFMA: af[8] prefetch, bf streamed per-j (keeps VGPR <= r8's 124)
    auto mfma_half = [&](const unsigned short* bufA, const unsigned short* bufB,
                         int kk) {
        half8 af[8];
        #pragma unroll
        for (int i = 0; i < 8; ++i)
            af[i] = *(const half8*)(bufA + (wm + i * 16 + fr) * BK + ((kk + fkb) ^ swz_r));
        __builtin_amdgcn_s_setprio(1);
        #pragma unroll
        for (int j = 0; j < 4; ++j) {
            half8 bf = *(const half8*)(bufB + (wn + j * 16 + fr) * BK + ((kk + fkb) ^ swz_r));
            #pragma unroll
            for (int i = 0; i < 8; ++i)
                acc[i][j] = __builtin_amdgcn_mfma_f32_16x16x32_f16(
                    af[i], bf, acc[i][j], 0, 0, 0);
        }
        __builtin_amdgcn_s_setprio(0);
    };

    // prologue: tile 0 staged, tile 1 loads in flight
    load_tile(0);
    stage_tile(sA[0], sB[0]);
    load_tile(BK);
    __syncthreads();

    for (int t = 0; t < NT; ++t) {
        const unsigned short* bufA = sA[t & 1];
        const unsigned short* bufB = sB[t & 1];

        // first half of tile t
        mfma_half(bufA, bufB, 0);

        // stage t+1 into the other buffer (its readers all passed the barrier
        // at end of t-1), then issue loads for t+2 (consumed next iteration)
        if (t + 1 < NT) stage_tile(sA[(t + 1) & 1], sB[(t + 1) & 1]);
        if (t + 2 < NT) load_tile((t + 2) * BK);

        // second half of tile t
        mfma_half(bufA, bufB, 32);

        __syncthreads();   // stage(t+1) complete for all waves
    }

    // epilogue: C/D layout col=lane&15, row=(lane>>4)*4+reg  [m89/m91]
    float bv[4];
    #pragma unroll
    for (int j = 0; j < 4; ++j)
        bv[j] = bias[n0 + wn + j * 16 + fr];

    const int r0 = (lane >> 4) * 4;
    #pragma unroll
    for (int i = 0; i < 8; ++i) {
        #pragma unroll
        for (int r = 0; r < 4; ++r) {
            long row = m0 + wm + i * 16 + r0 + r;
            float* cp = C + row * Ndim + n0 + wn + fr;
            #pragma unroll
            for (int j = 0; j < 4; ++j)
                __builtin_nontemporal_store(acc[i][j][r] + bv[j], cp + j * 16);
        }
    }
}

extern "C" void kernel_launch(void* const* d_in, const int* in_sizes, int n_in,
                              void* d_out, int out_size, void* d_ws, size_t ws_size,
                              hipStream_t stream) {
    const float* x     = (const float*)d_in[0];  // fp32 [B,S,IN]
    const int*   w     = (const int*)d_in[1];    // int32 [OUT,IN]
    const float* scale = (const float*)d_in[2];  // fp32 [OUT,IN/128]
    const float* bias  = (const float*)d_in[3];  // fp32 [OUT]
    float* out = (float*)d_out;                  // fp32 [B,S,OUT]

    wq8_gemm_kernel<<<dim3(NBX * NBY), 512, 0, stream>>>(x, w, scale, bias, out);
}